// Round 3
// baseline (164.351 us; speedup 1.0000x reference)
//
#include <hip/hip_runtime.h>

// ForgetMult: h_t = f_t*x_t + (1-f_t)*h_{t-1}, independent per (b,h) channel.
// R2: back to the R0 structure (passed harness) with the latency fix R0
// needed: one thread per channel, scalar fp32, 512 blocks x 64 = 2 waves/CU.
//
// Per group of U=32 timesteps: load-phase (64 global loads into static-indexed
// register arrays = 16 KB/wave in flight), sched_barrier(0), then the FMA
// chain + stores. The barrier stops the compiler from sinking loads into the
// compute phase (R0's failure: only ~10 loads in flight -> 2.9 TB/s); it does
// NOT stop it from hoisting group g+1's loads into group g's compute.
// In-flight bytes: 16 KB/wave x 2 waves/CU = 32 KB >> 9.2 KB needed to cover
// ~900 cy HBM latency at 6.3 TB/s.
//
// __launch_bounds__(64, 2): 256-VGPR cap -- room for the 64-register batch
// (~100 VGPRs total) without the 512-VGPR single-wave mode R1 used.

constexpr int U = 32;  // timesteps per group; T=2048 -> 64 groups

__global__ __launch_bounds__(64, 2) void forget_mult_kernel(
    const float* __restrict__ x, const float* __restrict__ f,
    const float* __restrict__ h0, float* __restrict__ out,
    int T, int H) {
  const int tid = blockIdx.x * blockDim.x + threadIdx.x;  // [0, B*H)
  const int b = tid / H;
  const int h = tid - b * H;
  int base = b * T * H + h;  // B*T*H = 67,108,864 < 2^31

  float hv = h0[tid];

  for (int g = 0; g < T; g += U) {
    float xa[U], fa[U];
    // Load phase: 2*U independent loads, static indices -> stays in VGPRs.
#pragma unroll
    for (int u = 0; u < U; ++u) {
      xa[u] = x[base + u * H];
      fa[u] = f[base + u * H];
    }
    __builtin_amdgcn_sched_barrier(0);  // don't sink loads into the FMA chain
    // Compute phase: serial FMA chain (the recurrence) + coalesced stores.
#pragma unroll
    for (int u = 0; u < U; ++u) {
      hv = fmaf(1.0f - fa[u], hv, fa[u] * xa[u]);  // same formula as R0 (bit-exact pass)
      out[base + u * H] = hv;
    }
    base += U * H;
  }
}

extern "C" void kernel_launch(void* const* d_in, const int* in_sizes, int n_in,
                              void* d_out, int out_size, void* d_ws, size_t ws_size,
                              hipStream_t stream) {
  const float* x = (const float*)d_in[0];
  const float* f = (const float*)d_in[1];
  const float* h0 = (const float*)d_in[2];
  float* out = (float*)d_out;

  const int BH = in_sizes[2];      // B*H = 32768
  const int T = in_sizes[0] / BH;  // 2048
  const int H = 1024;              // per setup_inputs()

  const int block = 64;
  const int grid = BH / block;     // 512 blocks -> 2 waves/CU on 256 CUs
  forget_mult_kernel<<<grid, block, 0, stream>>>(x, f, h0, out, T, H);
}